// Round 15
// baseline (51.191 us; speedup 1.0000x reference)
//
#include <hip/hip_runtime.h>
#include <hip/hip_bf16.h>
#include <math.h>

#define D_DIM   1024
#define NM      16
#define B_DIM   8
#define L_DIM   4096
#define SCALE_F 0.25f      // sqrt(1/N)
#define NK      5          // MFMA K-steps of 32 -> 160 taps total
#define NITER   4          // batch rows per block (block = (d, bgrp))
#define SROW    8704       // staged row bytes: 4096 bf16 reversed + 512B zero-pad

typedef __attribute__((ext_vector_type(8))) short bf16x8;   // 8 bf16 (4 VGPRs)
typedef __attribute__((ext_vector_type(4))) float f32x4;

union U4 { uint4 u; bf16x8 v; };

__device__ __forceinline__ unsigned short f2bf(float f) {
    __hip_bfloat16 h = __float2bfloat16(f);               // RNE
    return *reinterpret_cast<unsigned short*>(&h);
}
__device__ __forceinline__ float bflo(unsigned u) { return __uint_as_float(u << 16); }
__device__ __forceinline__ float bfhi(unsigned u) { return __uint_as_float(u & 0xffff0000u); }
// 16B-slot XOR swizzle (write and read identically); >=8B-aligned accesses only.
__device__ __forceinline__ int swz(int a) { return a ^ (((a >> 7) & 7) << 4); }

// A-fragment for K-step k of dimension d (tap layout unchanged since R8):
// A[i,t'] = kernel_d[i + t'], lane=(i | g<<4), t' = 32k + 8g + e - 15.
__device__ void compute_af_k(int d, int lane, int k,
                             const float* __restrict__ p_logit,
                             const float* __restrict__ lqr,
                             const float* __restrict__ lqi,
                             const float* __restrict__ gr,
                             const float* __restrict__ gi,
                             char* __restrict__ afb)
{
    const int i = lane & 15, g = lane >> 4;
    const int t0 = i - 15 + 32 * k + 8 * g;
    const float t0f = (float)t0;

    float acc[8];
#pragma unroll
    for (int e = 0; e < 8; ++e) acc[e] = 0.0f;

#pragma unroll 1
    for (int n = 0; n < NM; ++n) {
        const int idx = d * NM + n;
        const float pp = 1.0f / (1.0f + __expf(-p_logit[idx]));
        const float CR = gr[idx] * (SCALE_F * pp);
        const float CI = gi[idx] * (SCALE_F * pp);
        const float LR = lqr[idx], LI = lqi[idx];

        float sq, cq; __sincosf(LI, &sq, &cq);
        const float eq = __expf(LR);
        const float qr = eq * cq, qi = eq * sq;          // q
        float s0, c0; __sincosf(t0f * LI, &s0, &c0);
        const float e0 = __expf(t0f * LR);
        float wr = e0 * c0, wi = e0 * s0;                // q^t0

#pragma unroll
        for (int e = 0; e < 8; ++e) {
            acc[e] = fmaf(CR, wr, fmaf(-CI, wi, acc[e]));
            const float nwr = fmaf(wr, qr, -wi * qi);
            const float nwi = fmaf(wr, qi,  wi * qr);
            wr = nwr; wi = nwi;
        }
    }

    unsigned pk[4];
#pragma unroll
    for (int e = 0; e < 8; ++e) {
        const unsigned b = (t0 + e >= 0) ? (unsigned)f2bf(acc[e]) : 0u;
        if ((e & 1) == 0) pk[e >> 1] = b; else pk[e >> 1] |= b << 16;
    }
    *reinterpret_cast<uint4*>(afb + k * 1024 + lane * 16) =
        make_uint4(pk[0], pk[1], pk[2], pk[3]);
}

// v10: R14 structure with grid 2048 (block = (d,bgrp), NITER=4) -> exactly
// 8 blocks/CU resident (32 waves/CU static 100%; R14's grid=1024 capped at
// 16 waves/CU and measured 34% from tail imbalance). To fit 8 blocks/CU in
// 160KB LDS, the af table is ALIASED onto stage-buffer 1: af bytes [0,5120)
// are consumed into registers (after barrier#1, before barrier#2) strictly
// before buf1's first pack (after i=0's compute, post barrier#2); the
// zero-pad [8192,8704) doesn't overlap. LDS 22.5 -> 17.4 KB/block.
// Reversed-row layout, swizzle, tap math byte-identical to R14 (absmax 0.0625).
__global__ __launch_bounds__(256)
void ema_fused(const float* __restrict__ x,
               const float* __restrict__ p_logit,
               const float* __restrict__ lqr, const float* __restrict__ lqi,
               const float* __restrict__ gr, const float* __restrict__ gi,
               const float* __restrict__ omega,
               float* __restrict__ out)
{
    __shared__ __align__(16) char sstage[2][SROW];   // 17 KB total; safb aliased
    char* safb = sstage[1];                          // af table: bytes [0,5120)

    const int tid  = threadIdx.x;
    const int w    = tid >> 6;                  // wave = quarter of the row
    const int lane = tid & 63;
    const int d    = blockIdx.x >> 1;
    const int bgrp = blockIdx.x & 1;            // rows bgrp*4 .. bgrp*4+3
    const int j    = lane & 15, g = lane >> 4;

    const size_t rstride = (size_t)D_DIM * L_DIM;
    const float* xrow0 = x   + (size_t)(bgrp * 4 * D_DIM + d) * L_DIM;
    float*       yrow0 = out + (size_t)(bgrp * 4 * D_DIM + d) * L_DIM;
    const float  om    = omega[d];

    // ---- zero pads of both buffers: bytes [8192,8704) = x[-256..-1] ----
    if (tid < 64) {
        const int buf = tid >> 5, h = tid & 31;
        *reinterpret_cast<uint4*>(sstage[buf] + swz(8192 + h * 16)) =
            make_uint4(0u, 0u, 0u, 0u);
    }

    // ---- issue row 0 loads (16 consecutive floats per thread) ----
    float4 r[4];
#pragma unroll
    for (int v = 0; v < 4; ++v)
        r[v] = *reinterpret_cast<const float4*>(xrow0 + tid * 16 + 4 * v);

    // ---- cooperative af into safb(=buf1 head): wave w -> k=w; wave 0 also k=4 ----
    compute_af_k(d, lane, w, p_logit, lqr, lqi, gr, gi, safb);
    if (w == 0)
        compute_af_k(d, lane, 4, p_logit, lqr, lqi, gr, gi, safb);

    __syncthreads();                            // barrier#1: af + pads visible

    bf16x8 af[NK];
#pragma unroll
    for (int k = 0; k < NK; ++k) {
        U4 u; u.u = *reinterpret_cast<const uint4*>(safb + k * 1024 + lane * 16);
        af[k] = u.v;
    }

    // Reversed pack: thread covers x[16tid..16tid+15] -> bytes 8160-32tid.
#define PACK(dst)                                                              \
    {                                                                          \
        unsigned pk[8];                                                        \
        pk[0] = (unsigned)f2bf(r[3].w) | ((unsigned)f2bf(r[3].z) << 16);       \
        pk[1] = (unsigned)f2bf(r[3].y) | ((unsigned)f2bf(r[3].x) << 16);       \
        pk[2] = (unsigned)f2bf(r[2].w) | ((unsigned)f2bf(r[2].z) << 16);       \
        pk[3] = (unsigned)f2bf(r[2].y) | ((unsigned)f2bf(r[2].x) << 16);       \
        pk[4] = (unsigned)f2bf(r[1].w) | ((unsigned)f2bf(r[1].z) << 16);       \
        pk[5] = (unsigned)f2bf(r[1].y) | ((unsigned)f2bf(r[1].x) << 16);       \
        pk[6] = (unsigned)f2bf(r[0].w) | ((unsigned)f2bf(r[0].z) << 16);       \
        pk[7] = (unsigned)f2bf(r[0].y) | ((unsigned)f2bf(r[0].x) << 16);       \
        const int base = 8160 - tid * 32;                                      \
        *reinterpret_cast<uint4*>((dst) + swz(base)) =                         \
            make_uint4(pk[0], pk[1], pk[2], pk[3]);                            \
        *reinterpret_cast<uint4*>((dst) + swz(base + 16)) =                    \
            make_uint4(pk[4], pk[5], pk[6], pk[7]);                            \
    }

    // ---- pack row 0 -> buf0, issue row 1 loads ----
    PACK(sstage[0]);
#pragma unroll
    for (int v = 0; v < 4; ++v)
        r[v] = *reinterpret_cast<const float4*>(xrow0 + rstride + tid * 16 + 4 * v);

    __syncthreads();                            // barrier#2: buf0 ready, af read done

#pragma unroll 1
    for (int i = 0; i < NITER; ++i) {
        const char* sb = sstage[i & 1];
        float* yb = yrow0 + (size_t)i * rstride + w * 1024;

        // ---- this wave's quarter: 4 tiles, direct ds_read_b128 ----
#pragma unroll
        for (int tt = 0; tt < 4; ++tt) {
            f32x4 acc = {0.0f, 0.0f, 0.0f, 0.0f};
#pragma unroll
            for (int k = 0; k < NK; ++k) {
                const int rboff = 8160 - 2048 * w - 512 * tt - 32 * j + 64 * k + 16 * g;
                U4 z; z.u = *reinterpret_cast<const uint4*>(sb + swz(rboff));
                acc = __builtin_amdgcn_mfma_f32_16x16x32_bf16(af[k], z.v, acc, 0, 0, 0);
            }
            const int roff = 8184 - 2048 * w - 512 * tt - 32 * j - 8 * g;
            const uint2 z2 = *reinterpret_cast<const uint2*>(sb + swz(roff));
            acc.x = fmaf(om, bfhi(z2.y), acc.x);
            acc.y = fmaf(om, bflo(z2.y), acc.y);
            acc.z = fmaf(om, bfhi(z2.x), acc.z);
            acc.w = fmaf(om, bflo(z2.x), acc.w);
            __builtin_nontemporal_store(acc,
                reinterpret_cast<f32x4*>(yb + tt * 256 + 16 * j + 4 * g));
        }

        // ---- stage row i+1 into the other buffer; issue row i+2 loads ----
        if (i < NITER - 1) {
            char* nb = sstage[(i + 1) & 1];
            PACK(nb);
            if (i < NITER - 2) {
#pragma unroll
                for (int v = 0; v < 4; ++v)
                    r[v] = *reinterpret_cast<const float4*>(
                        xrow0 + (size_t)(i + 2) * rstride + tid * 16 + 4 * v);
            }
            __syncthreads();                    // next buf ready; cur buf free
        }
    }
#undef PACK
}

extern "C" void kernel_launch(void* const* d_in, const int* in_sizes, int n_in,
                              void* d_out, int out_size, void* d_ws, size_t ws_size,
                              hipStream_t stream)
{
    const float* x   = (const float*)d_in[0];
    const float* pl  = (const float*)d_in[1];
    const float* lqr = (const float*)d_in[2];
    const float* lqi = (const float*)d_in[3];
    const float* gr  = (const float*)d_in[4];
    const float* gi  = (const float*)d_in[5];
    const float* om  = (const float*)d_in[6];
    float* out = (float*)d_out;

    dim3 grid(D_DIM * 2), block(256);   // 2048 blocks = exactly 8/CU resident
    ema_fused<<<grid, block, 0, stream>>>(x, pl, lqr, lqi, gr, gi, om, out);
}

// Round 16
// 49.223 us; speedup vs baseline: 1.0400x; 1.0400x over previous
//
#include <hip/hip_runtime.h>
#include <hip/hip_bf16.h>
#include <math.h>

#define D_DIM   1024
#define NM      16
#define B_DIM   8
#define L_DIM   4096
#define SCALE_F 0.25f      // sqrt(1/N)
#define NK      5          // MFMA K-steps of 32 -> 160 taps total
#define NITER   8          // all 8 batch rows per block (block = d, grid 1024)
#define SROW    8704       // staged row bytes: 4096 bf16 reversed + 512B zero-pad

typedef __attribute__((ext_vector_type(8))) short bf16x8;   // 8 bf16 (4 VGPRs)
typedef __attribute__((ext_vector_type(4))) float f32x4;

union U4 { uint4 u; bf16x8 v; };

__device__ __forceinline__ unsigned short f2bf(float f) {
    __hip_bfloat16 h = __float2bfloat16(f);               // RNE
    return *reinterpret_cast<unsigned short*>(&h);
}
__device__ __forceinline__ float bflo(unsigned u) { return __uint_as_float(u << 16); }
__device__ __forceinline__ float bfhi(unsigned u) { return __uint_as_float(u & 0xffff0000u); }
// 16B-slot XOR swizzle (write and read identically); >=8B-aligned accesses only.
__device__ __forceinline__ int swz(int a) { return a ^ (((a >> 7) & 7) << 4); }

// A-fragment for K-step k of dimension d (tap layout unchanged since R8):
// A[i,t'] = kernel_d[i + t'], lane=(i | g<<4), t' = 32k + 8g + e - 15.
__device__ void compute_af_k(int d, int lane, int k,
                             const float* __restrict__ p_logit,
                             const float* __restrict__ lqr,
                             const float* __restrict__ lqi,
                             const float* __restrict__ gr,
                             const float* __restrict__ gi,
                             char* __restrict__ afb)
{
    const int i = lane & 15, g = lane >> 4;
    const int t0 = i - 15 + 32 * k + 8 * g;
    const float t0f = (float)t0;

    float acc[8];
#pragma unroll
    for (int e = 0; e < 8; ++e) acc[e] = 0.0f;

#pragma unroll 1
    for (int n = 0; n < NM; ++n) {
        const int idx = d * NM + n;
        const float pp = 1.0f / (1.0f + __expf(-p_logit[idx]));
        const float CR = gr[idx] * (SCALE_F * pp);
        const float CI = gi[idx] * (SCALE_F * pp);
        const float LR = lqr[idx], LI = lqi[idx];

        float sq, cq; __sincosf(LI, &sq, &cq);
        const float eq = __expf(LR);
        const float qr = eq * cq, qi = eq * sq;          // q
        float s0, c0; __sincosf(t0f * LI, &s0, &c0);
        const float e0 = __expf(t0f * LR);
        float wr = e0 * c0, wi = e0 * s0;                // q^t0

#pragma unroll
        for (int e = 0; e < 8; ++e) {
            acc[e] = fmaf(CR, wr, fmaf(-CI, wi, acc[e]));
            const float nwr = fmaf(wr, qr, -wi * qi);
            const float nwi = fmaf(wr, qi,  wi * qr);
            wr = nwr; wi = nwi;
        }
    }

    unsigned pk[4];
#pragma unroll
    for (int e = 0; e < 8; ++e) {
        const unsigned b = (t0 + e >= 0) ? (unsigned)f2bf(acc[e]) : 0u;
        if ((e & 1) == 0) pk[e >> 1] = b; else pk[e >> 1] |= b << 16;
    }
    *reinterpret_cast<uint4*>(afb + k * 1024 + lane * 16) =
        make_uint4(pk[0], pk[1], pk[2], pk[3]);
}

// v11: R14's persistent grid-1024 (block = d, NITER=8, af once per block)
// with 512-THREAD blocks: 8 waves, wave = EIGHTH of the row (2 tiles/row).
// 4 blocks/CU x 8 waves = 32 waves/CU static (2x R14, whose measured 34%
// occupancy at 16 waves/CU left the HBM pipe at ~62%); per-wave serial chain
// halves. Staging: thread tid packs x[8tid..8tid+7] reversed into ONE uint4
// at byte 8176-16*tid. Tile index T = 2w+tt in [0,16): offsets
// 8160-512T-32j+64k+16g -- reversed layout, swizzle, af aliasing (buf1 head,
// consumed into regs before barrier#2, buf1 first packed after) all
// byte-identical to R14/R15 (absmax 0.0625 invariant).
__global__ __launch_bounds__(512)
void ema_fused(const float* __restrict__ x,
               const float* __restrict__ p_logit,
               const float* __restrict__ lqr, const float* __restrict__ lqi,
               const float* __restrict__ gr, const float* __restrict__ gi,
               const float* __restrict__ omega,
               float* __restrict__ out)
{
    __shared__ __align__(16) char sstage[2][SROW];   // 17 KB; af aliased on buf1
    char* safb = sstage[1];                          // af table: bytes [0,5120)

    const int tid  = threadIdx.x;
    const int w    = tid >> 6;                  // wave = eighth of the row
    const int lane = tid & 63;
    const int d    = blockIdx.x;
    const int j    = lane & 15, g = lane >> 4;

    const size_t rstride = (size_t)D_DIM * L_DIM;
    const float* xrow0 = x   + (size_t)d * L_DIM;
    float*       yrow0 = out + (size_t)d * L_DIM;
    const float  om    = omega[d];

    // ---- zero pads of both buffers: bytes [8192,8704) = x[-256..-1] ----
    if (tid < 64) {
        const int buf = tid >> 5, h = tid & 31;
        *reinterpret_cast<uint4*>(sstage[buf] + swz(8192 + h * 16)) =
            make_uint4(0u, 0u, 0u, 0u);
    }

    // ---- issue row 0 loads (8 consecutive floats per thread, 16KB/block) ----
    float4 r[2];
#pragma unroll
    for (int v = 0; v < 2; ++v)
        r[v] = *reinterpret_cast<const float4*>(xrow0 + tid * 8 + 4 * v);

    // ---- cooperative af into safb: waves 0..4 compute K-steps 0..4 ----
    if (w < NK)
        compute_af_k(d, lane, w, p_logit, lqr, lqi, gr, gi, safb);

    __syncthreads();                            // barrier#1: af + pads visible

    bf16x8 af[NK];
#pragma unroll
    for (int k = 0; k < NK; ++k) {
        U4 u; u.u = *reinterpret_cast<const uint4*>(safb + k * 1024 + lane * 16);
        af[k] = u.v;
    }

    // Reversed pack: thread covers x[8tid..8tid+7] -> one uint4 at 8176-16tid.
    // Word W holds {e=7-2W lo, e=6-2W hi}: r[1]=e4..e7, r[0]=e0..e3.
#define PACK(dst)                                                              \
    {                                                                          \
        unsigned pk0 = (unsigned)f2bf(r[1].w) | ((unsigned)f2bf(r[1].z) << 16);\
        unsigned pk1 = (unsigned)f2bf(r[1].y) | ((unsigned)f2bf(r[1].x) << 16);\
        unsigned pk2 = (unsigned)f2bf(r[0].w) | ((unsigned)f2bf(r[0].z) << 16);\
        unsigned pk3 = (unsigned)f2bf(r[0].y) | ((unsigned)f2bf(r[0].x) << 16);\
        *reinterpret_cast<uint4*>((dst) + swz(8176 - tid * 16)) =              \
            make_uint4(pk0, pk1, pk2, pk3);                                    \
    }

    // ---- pack row 0 -> buf0, issue row 1 loads ----
    PACK(sstage[0]);
#pragma unroll
    for (int v = 0; v < 2; ++v)
        r[v] = *reinterpret_cast<const float4*>(xrow0 + rstride + tid * 8 + 4 * v);

    __syncthreads();                            // barrier#2: buf0 ready, af read done

#pragma unroll 1
    for (int i = 0; i < NITER; ++i) {
        const char* sb = sstage[i & 1];
        float* yb = yrow0 + (size_t)i * rstride;

        // ---- this wave's eighth: 2 tiles, direct ds_read_b128 ----
#pragma unroll
        for (int tt = 0; tt < 2; ++tt) {
            const int T = 2 * w + tt;           // absolute tile 0..15
            f32x4 acc = {0.0f, 0.0f, 0.0f, 0.0f};
#pragma unroll
            for (int k = 0; k < NK; ++k) {
                const int rboff = 8160 - 512 * T - 32 * j + 64 * k + 16 * g;
                U4 z; z.u = *reinterpret_cast<const uint4*>(sb + swz(rboff));
                acc = __builtin_amdgcn_mfma_f32_16x16x32_bf16(af[k], z.v, acc, 0, 0, 0);
            }
            const int roff = 8184 - 512 * T - 32 * j - 8 * g;
            const uint2 z2 = *reinterpret_cast<const uint2*>(sb + swz(roff));
            acc.x = fmaf(om, bfhi(z2.y), acc.x);
            acc.y = fmaf(om, bflo(z2.y), acc.y);
            acc.z = fmaf(om, bfhi(z2.x), acc.z);
            acc.w = fmaf(om, bflo(z2.x), acc.w);
            __builtin_nontemporal_store(acc,
                reinterpret_cast<f32x4*>(yb + T * 256 + 16 * j + 4 * g));
        }

        // ---- stage row i+1 into the other buffer; issue row i+2 loads ----
        if (i < NITER - 1) {
            char* nb = sstage[(i + 1) & 1];
            PACK(nb);
            if (i < NITER - 2) {
#pragma unroll
                for (int v = 0; v < 2; ++v)
                    r[v] = *reinterpret_cast<const float4*>(
                        xrow0 + (size_t)(i + 2) * rstride + tid * 8 + 4 * v);
            }
            __syncthreads();                    // next buf ready; cur buf free
        }
    }
#undef PACK
}

extern "C" void kernel_launch(void* const* d_in, const int* in_sizes, int n_in,
                              void* d_out, int out_size, void* d_ws, size_t ws_size,
                              hipStream_t stream)
{
    const float* x   = (const float*)d_in[0];
    const float* pl  = (const float*)d_in[1];
    const float* lqr = (const float*)d_in[2];
    const float* lqi = (const float*)d_in[3];
    const float* gr  = (const float*)d_in[4];
    const float* gi  = (const float*)d_in[5];
    const float* om  = (const float*)d_in[6];
    float* out = (float*)d_out;

    dim3 grid(D_DIM), block(512);   // 1024 blocks = 4/CU, 32 waves/CU static
    ema_fused<<<grid, block, 0, stream>>>(x, pl, lqr, lqi, gr, gi, om, out);
}

// Round 17
// 48.834 us; speedup vs baseline: 1.0483x; 1.0080x over previous
//
#include <hip/hip_runtime.h>
#include <hip/hip_bf16.h>
#include <math.h>

#define D_DIM   1024
#define NM      16
#define B_DIM   8
#define L_DIM   4096
#define SCALE_F 0.25f      // sqrt(1/N)
#define NK      5          // MFMA K-steps of 32 -> 160 taps total
#define NITER   8          // all 8 batch rows per block (block = d, grid 1024)
#define SROW    8704       // staged row bytes: 4096 bf16 reversed + 512B zero-pad

typedef __attribute__((ext_vector_type(8))) short bf16x8;   // 8 bf16 (4 VGPRs)
typedef __attribute__((ext_vector_type(4))) float f32x4;

union U4 { uint4 u; bf16x8 v; };

__device__ __forceinline__ unsigned short f2bf(float f) {
    __hip_bfloat16 h = __float2bfloat16(f);               // RNE
    return *reinterpret_cast<unsigned short*>(&h);
}
__device__ __forceinline__ float bflo(unsigned u) { return __uint_as_float(u << 16); }
__device__ __forceinline__ float bfhi(unsigned u) { return __uint_as_float(u & 0xffff0000u); }
// 16B-slot XOR swizzle (write and read identically); >=8B-aligned accesses only.
__device__ __forceinline__ int swz(int a) { return a ^ (((a >> 7) & 7) << 4); }

// A-fragment for K-step k of dimension d (tap layout unchanged since R8):
// A[i,t'] = kernel_d[i + t'], lane=(i | g<<4), t' = 32k + 8g + e - 15.
__device__ void compute_af_k(int d, int lane, int k,
                             const float* __restrict__ p_logit,
                             const float* __restrict__ lqr,
                             const float* __restrict__ lqi,
                             const float* __restrict__ gr,
                             const float* __restrict__ gi,
                             char* __restrict__ afb)
{
    const int i = lane & 15, g = lane >> 4;
    const int t0 = i - 15 + 32 * k + 8 * g;
    const float t0f = (float)t0;

    float acc[8];
#pragma unroll
    for (int e = 0; e < 8; ++e) acc[e] = 0.0f;

#pragma unroll 1
    for (int n = 0; n < NM; ++n) {
        const int idx = d * NM + n;
        const float pp = 1.0f / (1.0f + __expf(-p_logit[idx]));
        const float CR = gr[idx] * (SCALE_F * pp);
        const float CI = gi[idx] * (SCALE_F * pp);
        const float LR = lqr[idx], LI = lqi[idx];

        float sq, cq; __sincosf(LI, &sq, &cq);
        const float eq = __expf(LR);
        const float qr = eq * cq, qi = eq * sq;          // q
        float s0, c0; __sincosf(t0f * LI, &s0, &c0);
        const float e0 = __expf(t0f * LR);
        float wr = e0 * c0, wi = e0 * s0;                // q^t0

#pragma unroll
        for (int e = 0; e < 8; ++e) {
            acc[e] = fmaf(CR, wr, fmaf(-CI, wi, acc[e]));
            const float nwr = fmaf(wr, qr, -wi * qi);
            const float nwi = fmaf(wr, qi,  wi * qr);
            wr = nwr; wi = nwi;
        }
    }

    unsigned pk[4];
#pragma unroll
    for (int e = 0; e < 8; ++e) {
        const unsigned b = (t0 + e >= 0) ? (unsigned)f2bf(acc[e]) : 0u;
        if ((e & 1) == 0) pk[e >> 1] = b; else pk[e >> 1] |= b << 16;
    }
    *reinterpret_cast<uint4*>(afb + k * 1024 + lane * 16) =
        make_uint4(pk[0], pk[1], pk[2], pk[3]);
}

// v12: R16 (512-thread persistent blocks, wave = eighth-row, reversed LDS
// layout, af aliased on buf1) with PACK-FIRST iteration order.
// gfx9 vmcnt counts STORES too: R16 issued the nontemporal stores right
// before PACK's s_waitcnt for its loads, putting a store-drain round-trip on
// the critical path every iteration. New order per iter: PACK row i+1
// (stores outstanding are from iter i-1, mostly drained; loads are 1 iter
// old) -> issue row i+2 loads -> compute row i -> barrier.
// Buffer safety: PACK@i targets buf[(i+1)&1], last read in iter i-1, and the
// end-of-(i-1) barrier ordered that read before this write; compute@i reads
// buf[i&1] written in iter i-1 and published by the same barrier.
__global__ __launch_bounds__(512)
void ema_fused(const float* __restrict__ x,
               const float* __restrict__ p_logit,
               const float* __restrict__ lqr, const float* __restrict__ lqi,
               const float* __restrict__ gr, const float* __restrict__ gi,
               const float* __restrict__ omega,
               float* __restrict__ out)
{
    __shared__ __align__(16) char sstage[2][SROW];   // 17 KB; af aliased on buf1
    char* safb = sstage[1];                          // af table: bytes [0,5120)

    const int tid  = threadIdx.x;
    const int w    = tid >> 6;                  // wave = eighth of the row
    const int lane = tid & 63;
    const int d    = blockIdx.x;
    const int j    = lane & 15, g = lane >> 4;

    const size_t rstride = (size_t)D_DIM * L_DIM;
    const float* xrow0 = x   + (size_t)d * L_DIM;
    float*       yrow0 = out + (size_t)d * L_DIM;
    const float  om    = omega[d];

    // ---- zero pads of both buffers: bytes [8192,8704) = x[-256..-1] ----
    if (tid < 64) {
        const int buf = tid >> 5, h = tid & 31;
        *reinterpret_cast<uint4*>(sstage[buf] + swz(8192 + h * 16)) =
            make_uint4(0u, 0u, 0u, 0u);
    }

    // ---- issue row 0 loads (8 consecutive floats per thread, 16KB/block) ----
    float4 r[2];
#pragma unroll
    for (int v = 0; v < 2; ++v)
        r[v] = *reinterpret_cast<const float4*>(xrow0 + tid * 8 + 4 * v);

    // ---- cooperative af into safb: waves 0..4 compute K-steps 0..4 ----
    if (w < NK)
        compute_af_k(d, lane, w, p_logit, lqr, lqi, gr, gi, safb);

    __syncthreads();                            // barrier#1: af + pads visible

    bf16x8 af[NK];
#pragma unroll
    for (int k = 0; k < NK; ++k) {
        U4 u; u.u = *reinterpret_cast<const uint4*>(safb + k * 1024 + lane * 16);
        af[k] = u.v;
    }

    // Reversed pack: thread covers x[8tid..8tid+7] -> one uint4 at 8176-16tid.
    // Word W holds {e=7-2W lo, e=6-2W hi}: r[1]=e4..e7, r[0]=e0..e3.
#define PACK(dst)                                                              \
    {                                                                          \
        unsigned pk0 = (unsigned)f2bf(r[1].w) | ((unsigned)f2bf(r[1].z) << 16);\
        unsigned pk1 = (unsigned)f2bf(r[1].y) | ((unsigned)f2bf(r[1].x) << 16);\
        unsigned pk2 = (unsigned)f2bf(r[0].w) | ((unsigned)f2bf(r[0].z) << 16);\
        unsigned pk3 = (unsigned)f2bf(r[0].y) | ((unsigned)f2bf(r[0].x) << 16);\
        *reinterpret_cast<uint4*>((dst) + swz(8176 - tid * 16)) =              \
            make_uint4(pk0, pk1, pk2, pk3);                                    \
    }

    // ---- pack row 0 -> buf0, issue row 1 loads ----
    PACK(sstage[0]);
#pragma unroll
    for (int v = 0; v < 2; ++v)
        r[v] = *reinterpret_cast<const float4*>(xrow0 + rstride + tid * 8 + 4 * v);

    __syncthreads();                            // barrier#2: buf0 ready, af read done

#pragma unroll 1
    for (int i = 0; i < NITER; ++i) {
        // ---- PACK row i+1 first (stores outstanding are a full iter old) ----
        if (i < NITER - 1) {
            PACK(sstage[(i + 1) & 1]);
            if (i < NITER - 2) {
#pragma unroll
                for (int v = 0; v < 2; ++v)
                    r[v] = *reinterpret_cast<const float4*>(
                        xrow0 + (size_t)(i + 2) * rstride + tid * 8 + 4 * v);
            }
        }

        // ---- compute row i: this wave's eighth, 2 tiles, direct ds_read ----
        const char* sb = sstage[i & 1];
        float* yb = yrow0 + (size_t)i * rstride;
#pragma unroll
        for (int tt = 0; tt < 2; ++tt) {
            const int T = 2 * w + tt;           // absolute tile 0..15
            f32x4 acc = {0.0f, 0.0f, 0.0f, 0.0f};
#pragma unroll
            for (int k = 0; k < NK; ++k) {
                const int rboff = 8160 - 512 * T - 32 * j + 64 * k + 16 * g;
                U4 z; z.u = *reinterpret_cast<const uint4*>(sb + swz(rboff));
                acc = __builtin_amdgcn_mfma_f32_16x16x32_bf16(af[k], z.v, acc, 0, 0, 0);
            }
            const int roff = 8184 - 512 * T - 32 * j - 8 * g;
            const uint2 z2 = *reinterpret_cast<const uint2*>(sb + swz(roff));
            acc.x = fmaf(om, bfhi(z2.y), acc.x);
            acc.y = fmaf(om, bflo(z2.y), acc.y);
            acc.z = fmaf(om, bfhi(z2.x), acc.z);
            acc.w = fmaf(om, bflo(z2.x), acc.w);
            __builtin_nontemporal_store(acc,
                reinterpret_cast<f32x4*>(yb + T * 256 + 16 * j + 4 * g));
        }

        if (i < NITER - 1)
            __syncthreads();                    // publish pack; order buf reuse
    }
#undef PACK
}

extern "C" void kernel_launch(void* const* d_in, const int* in_sizes, int n_in,
                              void* d_out, int out_size, void* d_ws, size_t ws_size,
                              hipStream_t stream)
{
    const float* x   = (const float*)d_in[0];
    const float* pl  = (const float*)d_in[1];
    const float* lqr = (const float*)d_in[2];
    const float* lqi = (const float*)d_in[3];
    const float* gr  = (const float*)d_in[4];
    const float* gi  = (const float*)d_in[5];
    const float* om  = (const float*)d_in[6];
    float* out = (float*)d_out;

    dim3 grid(D_DIM), block(512);   // 1024 blocks = 4/CU, 32 waves/CU static
    ema_fused<<<grid, block, 0, stream>>>(x, pl, lqr, lqi, gr, gi, om, out);
}